// Round 2
// baseline (105.036 us; speedup 1.0000x reference)
//
#include <hip/hip_runtime.h>
#include <hip/hip_bf16.h>

// out[b,u] = exp(-0.5 * (|x_b|^2 - 2*x.mu + |mu_u|^2))
// x: (65536, 64) f32 row-major; mu: (64, 256) f32 row-major; out: (65536, 256) f32.
// bf16 MFMA (16x16x32) for the cross term; |x|^2 / |mu|^2 in fp32 from originals.
// Grid 1024 blocks x 4 row-tiles each; 2-deep pipelined x loads; NT loads/stores
// for the streamed x/out (no reuse), mu stays cached.

typedef __attribute__((ext_vector_type(8))) short short8;   // 8 bf16 (4 VGPRs)
typedef __attribute__((ext_vector_type(4))) float floatx4;  // MFMA C/D frag

#define GRIDB 1024
#define TILES 4   // 1024 * 4 * 16 rows = 65536

__device__ inline short f2bf_rne(float f) {
    unsigned int u = __float_as_uint(f);
    u += 0x7fffu + ((u >> 16) & 1u);   // round-to-nearest-even (no NaN in data)
    return (short)(u >> 16);
}

__device__ inline floatx4 ldnt4(const float* p) {
    return __builtin_nontemporal_load((const floatx4*)p);
}

__global__ __launch_bounds__(256, 4) void rbf_kernel(
    const float* __restrict__ x, const float* __restrict__ mu,
    float* __restrict__ out)
{
    const int tid  = threadIdx.x;
    const int wave = tid >> 6;       // 0..3, owns u in [64*wave, 64*wave+64)
    const int lane = tid & 63;
    const int l15  = lane & 15;
    const int g    = lane >> 4;      // 0..3
    const int ubase = wave * 64;

    // ---- B (mu) fragments: loaded once per block, register-resident ----
    // frag layout (16x16x32 bf16): lane holds B[k = 32h + 8g + e][u0 + l15]
    short8 bfrag[4][2];
    float  msq[4];                   // -0.5 * |mu_u|^2 for col of tile t
    #pragma unroll
    for (int t = 0; t < 4; ++t) {
        const int u = ubase + t * 16 + l15;
        float sq = 0.f;
        #pragma unroll
        for (int h = 0; h < 2; ++h) {
            short8 bf;
            const int k0 = 32 * h + 8 * g;
            #pragma unroll
            for (int e = 0; e < 8; ++e) {
                float v = mu[(k0 + e) * 256 + u];
                sq += v * v;
                bf[e] = f2bf_rne(v);
            }
            bfrag[t][h] = bf;
        }
        sq += __shfl_xor(sq, 16);
        sq += __shfl_xor(sq, 32);
        msq[t] = -0.5f * sq;
    }

    // ---- 4 row-tiles per block, 2-deep pipelined x loads ----
    int rt = blockIdx.x;
    const float* xr0 = x + (size_t)(rt * 16 + l15) * 64 + 8 * g;
    floatx4 c0 = ldnt4(xr0), c1 = ldnt4(xr0 + 4),
            c2 = ldnt4(xr0 + 32), c3 = ldnt4(xr0 + 36);

    #pragma unroll
    for (int i = 0; i < TILES; ++i) {
        floatx4 n0, n1, n2, n3;
        if (i + 1 < TILES) {
            const float* xn = x + (size_t)((rt + GRIDB) * 16 + l15) * 64 + 8 * g;
            n0 = ldnt4(xn); n1 = ldnt4(xn + 4);
            n2 = ldnt4(xn + 32); n3 = ldnt4(xn + 36);
        }

        // A frag: lane holds x[b0 + l15][k = 32h + 8g + e]; fp32 |x|^2 alongside
        short8 a0, a1;
        float xsq = 0.f;
        #pragma unroll
        for (int e = 0; e < 4; ++e) {
            xsq += c0[e] * c0[e] + c1[e] * c1[e];
            xsq += c2[e] * c2[e] + c3[e] * c3[e];
            a0[e]     = f2bf_rne(c0[e]);
            a0[e + 4] = f2bf_rne(c1[e]);
            a1[e]     = f2bf_rne(c2[e]);
            a1[e + 4] = f2bf_rne(c3[e]);
        }
        xsq += __shfl_xor(xsq, 16);
        xsq += __shfl_xor(xsq, 32);
        float xh[4];
        #pragma unroll
        for (int r = 0; r < 4; ++r)
            xh[r] = -0.5f * __shfl(xsq, 4 * g + r);   // row b0 + 4g + r

        const int b0 = rt * 16;
        #pragma unroll
        for (int t = 0; t < 4; ++t) {
            floatx4 acc = {0.f, 0.f, 0.f, 0.f};
            acc = __builtin_amdgcn_mfma_f32_16x16x32_bf16(a0, bfrag[t][0], acc, 0, 0, 0);
            acc = __builtin_amdgcn_mfma_f32_16x16x32_bf16(a1, bfrag[t][1], acc, 0, 0, 0);
            const int u = ubase + t * 16 + l15;
            #pragma unroll
            for (int r = 0; r < 4; ++r) {
                float arg = acc[r] + xh[r] + msq[t];
                __builtin_nontemporal_store(__expf(arg),
                    &out[(size_t)(b0 + 4 * g + r) * 256 + u]);
            }
        }

        if (i + 1 < TILES) {
            c0 = n0; c1 = n1; c2 = n2; c3 = n3;
            rt += GRIDB;
        }
    }
}

extern "C" void kernel_launch(void* const* d_in, const int* in_sizes, int n_in,
                              void* d_out, int out_size, void* d_ws, size_t ws_size,
                              hipStream_t stream) {
    const float* x  = (const float*)d_in[0];   // (65536, 64)
    const float* mu = (const float*)d_in[1];   // (64, 256)
    float* out = (float*)d_out;                // (65536, 256)
    hipLaunchKernelGGL(rbf_kernel, dim3(GRIDB), dim3(256), 0, stream, x, mu, out);
}

// Round 4
// 88.242 us; speedup vs baseline: 1.1903x; 1.1903x over previous
//
#include <hip/hip_runtime.h>
#include <hip/hip_bf16.h>

// out[b,u] = exp(-0.5 * (|x_b|^2 - 2*x.mu + |mu_u|^2))
// x: (65536, 64) f32 row-major; mu: (64, 256) f32 row-major; out: (65536, 256) f32.
// bf16 MFMA (16x16x32) for the cross term; |x|^2 / |mu|^2 in fp32 from originals.
// Grid 1024 blocks x 4 row-tiles each; 2-deep pipelined x loads.
// (Identical to round-3 source; round 3 died on container infra, never ran.)
// A/B vs round 2: ALL memory ops back to plain (no nontemporal) --
// stores fully cover 64B lines so L2 write-allocate absorbs them at fill rate;
// NT was suspected to defeat that (round-2 regression 92->105us).

typedef __attribute__((ext_vector_type(8))) short short8;   // 8 bf16 (4 VGPRs)
typedef __attribute__((ext_vector_type(4))) float floatx4;  // MFMA C/D frag

#define GRIDB 1024
#define TILES 4   // 1024 * 4 * 16 rows = 65536

__device__ inline short f2bf_rne(float f) {
    unsigned int u = __float_as_uint(f);
    u += 0x7fffu + ((u >> 16) & 1u);   // round-to-nearest-even (no NaN in data)
    return (short)(u >> 16);
}

__global__ __launch_bounds__(256, 4) void rbf_kernel(
    const float* __restrict__ x, const float* __restrict__ mu,
    float* __restrict__ out)
{
    const int tid  = threadIdx.x;
    const int wave = tid >> 6;       // 0..3, owns u in [64*wave, 64*wave+64)
    const int lane = tid & 63;
    const int l15  = lane & 15;
    const int g    = lane >> 4;      // 0..3
    const int ubase = wave * 64;

    // ---- B (mu) fragments: loaded once per block, register-resident ----
    // frag layout (16x16x32 bf16): lane holds B[k = 32h + 8g + e][u0 + l15]
    short8 bfrag[4][2];
    float  msq[4];                   // -0.5 * |mu_u|^2 for col of tile t
    #pragma unroll
    for (int t = 0; t < 4; ++t) {
        const int u = ubase + t * 16 + l15;
        float sq = 0.f;
        #pragma unroll
        for (int h = 0; h < 2; ++h) {
            short8 bf;
            const int k0 = 32 * h + 8 * g;
            #pragma unroll
            for (int e = 0; e < 8; ++e) {
                float v = mu[(k0 + e) * 256 + u];
                sq += v * v;
                bf[e] = f2bf_rne(v);
            }
            bfrag[t][h] = bf;
        }
        sq += __shfl_xor(sq, 16);
        sq += __shfl_xor(sq, 32);
        msq[t] = -0.5f * sq;
    }

    // ---- 4 row-tiles per block, 2-deep pipelined x loads ----
    int rt = blockIdx.x;
    const float* xr0 = x + (size_t)(rt * 16 + l15) * 64 + 8 * g;
    floatx4 c0 = *(const floatx4*)(xr0);
    floatx4 c1 = *(const floatx4*)(xr0 + 4);
    floatx4 c2 = *(const floatx4*)(xr0 + 32);
    floatx4 c3 = *(const floatx4*)(xr0 + 36);

    #pragma unroll
    for (int i = 0; i < TILES; ++i) {
        floatx4 n0, n1, n2, n3;
        if (i + 1 < TILES) {
            const float* xn = x + (size_t)((rt + GRIDB) * 16 + l15) * 64 + 8 * g;
            n0 = *(const floatx4*)(xn);
            n1 = *(const floatx4*)(xn + 4);
            n2 = *(const floatx4*)(xn + 32);
            n3 = *(const floatx4*)(xn + 36);
        }

        // A frag: lane holds x[b0 + l15][k = 32h + 8g + e]; fp32 |x|^2 alongside
        short8 a0, a1;
        float xsq = 0.f;
        #pragma unroll
        for (int e = 0; e < 4; ++e) {
            xsq += c0[e] * c0[e] + c1[e] * c1[e];
            xsq += c2[e] * c2[e] + c3[e] * c3[e];
            a0[e]     = f2bf_rne(c0[e]);
            a0[e + 4] = f2bf_rne(c1[e]);
            a1[e]     = f2bf_rne(c2[e]);
            a1[e + 4] = f2bf_rne(c3[e]);
        }
        xsq += __shfl_xor(xsq, 16);
        xsq += __shfl_xor(xsq, 32);
        float xh[4];
        #pragma unroll
        for (int r = 0; r < 4; ++r)
            xh[r] = -0.5f * __shfl(xsq, 4 * g + r);   // row b0 + 4g + r

        const int b0 = rt * 16;
        #pragma unroll
        for (int t = 0; t < 4; ++t) {
            floatx4 acc = {0.f, 0.f, 0.f, 0.f};
            acc = __builtin_amdgcn_mfma_f32_16x16x32_bf16(a0, bfrag[t][0], acc, 0, 0, 0);
            acc = __builtin_amdgcn_mfma_f32_16x16x32_bf16(a1, bfrag[t][1], acc, 0, 0, 0);
            const int u = ubase + t * 16 + l15;
            #pragma unroll
            for (int r = 0; r < 4; ++r) {
                float arg = acc[r] + xh[r] + msq[t];
                out[(size_t)(b0 + 4 * g + r) * 256 + u] = __expf(arg);
            }
        }

        if (i + 1 < TILES) {
            c0 = n0; c1 = n1; c2 = n2; c3 = n3;
            rt += GRIDB;
        }
    }
}

extern "C" void kernel_launch(void* const* d_in, const int* in_sizes, int n_in,
                              void* d_out, int out_size, void* d_ws, size_t ws_size,
                              hipStream_t stream) {
    const float* x  = (const float*)d_in[0];   // (65536, 64)
    const float* mu = (const float*)d_in[1];   // (64, 256)
    float* out = (float*)d_out;                // (65536, 256)
    hipLaunchKernelGGL(rbf_kernel, dim3(GRIDB), dim3(256), 0, stream, x, mu, out);
}